// Round 11
// baseline (15482.793 us; speedup 1.0000x reference)
//
#include <hip/hip_runtime.h>

// LSTM-CRF on MI355X.
// Pipeline: embed -> gemm(gin L0) -> lstm L0 -> gemm(gin L1) -> lstm L1 -> feats -> viterbi.
// Recurrence: 32 WGs per direction (16 units each), parallel dirs (round-7/10 structure).
// h exchanged per step via tagged u64 {tag:u32, h:f32} device-scope relaxed mailbox.
// Round-11: (1) 3-deep pipelined poll -- three same-address loads rotate in flight, so the
// sampling period is ~(latency+2*body)/3 ~ 240cy instead of one sample per ~700cy round;
// (2) manual pairwise tree-sum in wave0's finish (f32 reassociation is illegal for the
// compiler); (3) viterbi: 16 tags x 4 prev-groups in one wave, shfl_xor argmax tree,
// feats prefetch; (4) float4 B-staging in the GEMM; (5) zero_k dropped (all pad reads
// are multiplied by explicitly-zeroed B/W entries; 0xAA poison is finite).

#define T_SEQ 4096
#define HPAD  512
#define NTAG  16

// ---------------- workspace layout (bytes) ----------------
// x0   : [4096][512]  f32   8388608  @ 0
// x1   : [4096][1024] f32  16777216  @ 8388608
// x2   : [4096][1024] f32  16777216  @ 25165824
// gin  : [2][4096][2048] f32 67108864 @ 41943040
// feats: [4096][16] f32     262144  @ 109051904
// bptr : [4096][16] i32     262144  @ 109314048
// hcomm: [2][2][512] u64     16384  @ 109576192

__global__ void embed_k(const int* __restrict__ sent, const float* __restrict__ ew,
                        float* __restrict__ x0) {
  int t = blockIdx.x;
  int row = sent[t];
  for (int k = threadIdx.x; k < HPAD; k += blockDim.x)
    x0[(size_t)t * HPAD + k] = (k < 500) ? ew[(size_t)row * 500 + k] : 0.0f;
}

// G[dir][t][n] = sum_k A[t][k] * Wmap[dir][n][k] + bias[n]  (f32, 128x128 tile, 8x8/thread)
__global__ __launch_bounds__(256) void gin_gemm_k(
    const float* __restrict__ A, int KA,
    const float* __restrict__ wih, const float* __restrict__ bih,
    const float* __restrict__ bhh, int Kreal, float* __restrict__ G) {
  const int dir = blockIdx.z;
  const int bm = blockIdx.y, bn = blockIdx.x;
  const float* W = wih + (size_t)dir * 2000 * Kreal;

  __shared__ float As[16][128];
  __shared__ float Bs[16][128];

  const int tid = threadIdx.x;
  const int tx = tid & 15, ty = tid >> 4;
  float acc[8][8] = {};

  for (int k0 = 0; k0 < KA; k0 += 16) {
#pragma unroll
    for (int q = 0; q < 2; q++) {
      int f4 = tid + q * 256;              // 0..511
      int m = f4 >> 2, kc = (f4 & 3) * 4;
      float4 av = *reinterpret_cast<const float4*>(A + (size_t)(bm * 128 + m) * KA + k0 + kc);
      As[kc + 0][m] = av.x; As[kc + 1][m] = av.y;
      As[kc + 2][m] = av.z; As[kc + 3][m] = av.w;
    }
#pragma unroll
    for (int q = 0; q < 2; q++) {
      int f4 = tid + q * 256;
      int n = f4 >> 2, kc = (f4 & 3) * 4;
      int nn = bn * 128 + n;
      int gate = nn >> 9, j = nn & 511;
      int k = k0 + kc;
      int jk = k & 511, half = k >> 9;
      // jk is a multiple of 4, so jk<500 => jk<=496 => all 4 elements valid.
      // W row bases are multiples of 16B (500*4, 1000*4, 2000B all 16-aligned).
      float4 bv = {0.0f, 0.0f, 0.0f, 0.0f};
      if (j < 500 && jk < 500)
        bv = *reinterpret_cast<const float4*>(
            &W[(size_t)(gate * 500 + j) * Kreal + half * 500 + jk]);
      Bs[kc + 0][n] = bv.x; Bs[kc + 1][n] = bv.y;
      Bs[kc + 2][n] = bv.z; Bs[kc + 3][n] = bv.w;
    }
    __syncthreads();
#pragma unroll
    for (int kk = 0; kk < 16; kk++) {
      float a[8], b[8];
      *reinterpret_cast<float4*>(&a[0]) = *reinterpret_cast<const float4*>(&As[kk][ty * 8]);
      *reinterpret_cast<float4*>(&a[4]) = *reinterpret_cast<const float4*>(&As[kk][ty * 8 + 4]);
      *reinterpret_cast<float4*>(&b[0]) = *reinterpret_cast<const float4*>(&Bs[kk][tx * 8]);
      *reinterpret_cast<float4*>(&b[4]) = *reinterpret_cast<const float4*>(&Bs[kk][tx * 8 + 4]);
#pragma unroll
      for (int i = 0; i < 8; i++)
#pragma unroll
        for (int j = 0; j < 8; j++) acc[i][j] = fmaf(a[i], b[j], acc[i][j]);
    }
    __syncthreads();
  }
#pragma unroll
  for (int i = 0; i < 8; i++) {
#pragma unroll
    for (int j = 0; j < 8; j++) {
      int m = bm * 128 + ty * 8 + i;
      int nn = bn * 128 + tx * 8 + j;
      int gate = nn >> 9, ju = nn & 511;
      float o = 0.0f;
      if (ju < 500) {
        int r = gate * 500 + ju;
        o = acc[i][j] + bih[dir * 2000 + r] + bhh[dir * 2000 + r];
      }
      G[((size_t)dir * T_SEQ + m) * 2048 + nn] = o;
    }
  }
}

__device__ __forceinline__ unsigned long long pack_hv(unsigned tag, float h) {
  return (unsigned long long)tag | ((unsigned long long)__float_as_uint(h) << 32);
}

// fast sigmoid/tanh: v_exp_f32 + v_rcp_f32, branch-free, saturates correctly.
__device__ __forceinline__ float fsig(float x) {
  float e = __expf(-x);
  return __builtin_amdgcn_rcpf(1.0f + e);
}
__device__ __forceinline__ float ftanhf(float x) {
  return fmaf(2.0f, fsig(x + x), -1.0f);
}

__global__ void hinit_k(const float* __restrict__ h0, int layer,
                        unsigned long long* __restrict__ hcomm) {
  int i = blockIdx.x * blockDim.x + threadIdx.x;   // 0..2047
  int dir = i >> 10, par = (i >> 9) & 1, j = i & 511;
  unsigned long long v;
  if (par == 0) {
    float h = (j < 500) ? h0[(layer * 2 + dir) * 500 + j] : 0.0f;
    v = pack_hv(0u, h);
  } else {
    v = 0xFFFFFFFFull;   // sentinel tag, value 0
  }
  hcomm[(size_t)(dir * 2 + par) * HPAD + j] = v;
}

// Persistent recurrence kernel: 64 WGs x 1024 threads; WG = (dir = blockIdx>>5,
// wgd = blockIdx&31) owns units [wgd*16, wgd*16+16)  (64 rows = 4 gates x 16 units).
// Wave w owns k-slice [w*32, w*32+32); lane owns ONE row (gate=lane>>4, unit=lane&15).
// One barrier per step; wave0 sums 16 partials per row (pairwise tree), fast gates,
// publishes. Poll is 3-deep pipelined.
__global__ __launch_bounds__(1024)
__attribute__((amdgpu_waves_per_eu(4, 4)))
void lstm_k(
    const float* __restrict__ whh_base,   // [2][2000][500]
    const float* __restrict__ gin,        // [2][4096][2048]
    const float* __restrict__ c0,         // [4][500]
    float* __restrict__ xout,             // [4096][1024]
    unsigned long long* __restrict__ hcomm, // [2][2][512]
    int layer) {
  __shared__ float part[16][68];          // pad 68: conflict-free on both patterns
  __shared__ float hbuf[16][32];

  const int tid = threadIdx.x;
  const int dir = blockIdx.x >> 5;
  const int wgd = blockIdx.x & 31;        // unit block [wgd*16, wgd*16+16)
  const int w = tid >> 6;
  const int lane = tid & 63;

  const int gate = lane >> 4;             // my row's gate (0=i,1=f,2=g,3=o)
  const int ul   = lane & 15;             // my row's local unit
  const int j    = wgd * 16 + ul;         // global unit (0..511)
  const int row  = gate * 500 + j;

  // ---- load recurrent weights into registers (1 row x 32 k per lane) ----
  float wreg[32];
  const float* Wd = whh_base + (size_t)dir * 2000 * 500;
#pragma unroll
  for (int i = 0; i < 32; i++) {
    int k = w * 32 + i;
    wreg[i] = (j < 500 && k < 500) ? Wd[(size_t)row * 500 + k] : 0.0f;
  }
#pragma unroll
  for (int i = 0; i < 32; i++) asm volatile("" : "+v"(wreg[i]));

  // wave0 lanes<16: persistent cell state (one unit per lane)
  float c = 0.0f;
  if (w == 0 && lane < 16 && j < 500) c = c0[(layer * 2 + dir) * 500 + j];

  unsigned long long* hcd = hcomm + (size_t)dir * 2 * HPAD;
  bool dead = false;

  for (int t = 0; t < T_SEQ; t++) {
    const int t_in = (dir == 0) ? t : (T_SEQ - 1 - t);

    // prefetch input-projection gate value for my row (latency hidden under poll)
    float gi = 0.0f;
    if (w == 0) {
      const float* gb = gin + ((size_t)dir * T_SEQ + t_in) * 2048;
      gi = gb[gate * 512 + j];
    }

    // ---- 3-deep pipelined poll of my h slot (tag==t), device-scope ----
    unsigned long long v = 0;
    if (!dead) {
      const unsigned long long* hp =
          hcd + (size_t)(t & 1) * HPAD + w * 32 + (lane & 31);
      unsigned long long va = __hip_atomic_load(hp, __ATOMIC_RELAXED, __HIP_MEMORY_SCOPE_AGENT);
      unsigned long long vb = __hip_atomic_load(hp, __ATOMIC_RELAXED, __HIP_MEMORY_SCOPE_AGENT);
      unsigned long long vc = __hip_atomic_load(hp, __ATOMIC_RELAXED, __HIP_MEMORY_SCOPE_AGENT);
      int guard = 0;
      for (;;) {
        if (__all((int)((unsigned)va == (unsigned)t))) { v = va; break; }
        va = vb; vb = vc;
        vc = __hip_atomic_load(hp, __ATOMIC_RELAXED, __HIP_MEMORY_SCOPE_AGENT);
        if (++guard > (1 << 22)) { dead = true; break; }   // bail, never hang
      }
    }
    float hval = __uint_as_float((unsigned)(v >> 32));

    // ---- broadcast h within the wave via LDS, matvec partial for my row ----
    if (lane < 32) hbuf[w][lane] = hval;   // same-wave RAW, ordered by lgkmcnt
    float a = 0.0f;
#pragma unroll
    for (int b = 0; b < 8; b++) {
      float4 hv = *reinterpret_cast<const float4*>(&hbuf[w][b * 4]);
      a = fmaf(wreg[b * 4 + 0], hv.x, a);
      a = fmaf(wreg[b * 4 + 1], hv.y, a);
      a = fmaf(wreg[b * 4 + 2], hv.z, a);
      a = fmaf(wreg[b * 4 + 3], hv.w, a);
    }
    part[w][lane] = a;
    __syncthreads();   // the ONLY barrier per step

    // ---- wave0: pairwise tree-sum of 16 partials, fast gates, publish ----
    // Race-free vs next step: waves can only overwrite part(t+1) after polling
    // h(t+1), which requires the publish below -- which follows these reads.
    if (w == 0) {
      __builtin_amdgcn_s_setprio(1);       // win issue arbitration vs spinning waves
      float p0 = part[0][lane] + part[1][lane];
      float p1 = part[2][lane] + part[3][lane];
      float p2 = part[4][lane] + part[5][lane];
      float p3 = part[6][lane] + part[7][lane];
      float p4 = part[8][lane] + part[9][lane];
      float p5 = part[10][lane] + part[11][lane];
      float p6 = part[12][lane] + part[13][lane];
      float p7 = part[14][lane] + part[15][lane];
      float q0 = p0 + p1, q1 = p2 + p3, q2 = p4 + p5, q3 = p6 + p7;
      float s = gi + ((q0 + q1) + (q2 + q3));
      float nl = (gate == 2) ? ftanhf(s) : fsig(s);
      float xf = __shfl(nl, lane + 16, 64);
      float xg = __shfl(nl, lane + 32, 64);
      float xo = __shfl(nl, lane + 48, 64);
      if (lane < 16) {
        c = xf * c + nl * xg;              // nl here is xi (gate 0)
        float h = xo * ftanhf(c);
        // publish FIRST (starts the LLC trip), then the xout store
        __hip_atomic_store(hcd + (size_t)((t + 1) & 1) * HPAD + j,
                           pack_hv((unsigned)(t + 1), h),
                           __ATOMIC_RELAXED, __HIP_MEMORY_SCOPE_AGENT);
        if (j < 500)
          xout[(size_t)t_in * 1024 + (size_t)dir * HPAD + j] = h;
      }
      __builtin_amdgcn_s_setprio(0);
    }
  }
}

// feats[t][tag] = sum_k x2[t][k]*w_out[tag][k_real] + b_out[tag]
__global__ __launch_bounds__(256) void feats_k(
    const float* __restrict__ x2, const float* __restrict__ w_out,
    const float* __restrict__ b_out, float* __restrict__ feats) {
  int tid = threadIdx.x;
  int tag = tid & 15, tl = tid >> 4;
  int t = blockIdx.x * 16 + tl;
  float a0 = 0.0f, a1 = 0.0f, a2 = 0.0f, a3 = 0.0f;
  for (int k = 0; k < 1024; k += 4) {
    int jk = k & 511;   // k%4==0 so all 4 share the same half; jk+3<500 iff jk<500-3
    const float* xr = x2 + (size_t)t * 1024 + k;
    const float* wr = w_out + tag * 1000 + (k >> 9) * 500 + jk;
    if (jk + 3 < 500) {
      a0 = fmaf(xr[0], wr[0], a0);
      a1 = fmaf(xr[1], wr[1], a1);
      a2 = fmaf(xr[2], wr[2], a2);
      a3 = fmaf(xr[3], wr[3], a3);
    } else if (jk < 500) {
#pragma unroll
      for (int e = 0; e < 4; e++)
        if (jk + e < 500) a0 = fmaf(xr[e], wr[e], a0);
    }
  }
  feats[t * 16 + tag] = ((a0 + a1) + (a2 + a3)) + b_out[tag];
}

// Viterbi: one wave. lane = pg*16 + tag (pg = prev-group of 4). Tree argmax with
// np.argmax tie-break (smallest prev index). feats prefetched one step ahead.
__global__ __launch_bounds__(64) void viterbi_k(
    const float* __restrict__ feats, const float* __restrict__ trans,
    int* __restrict__ bptr, float* __restrict__ out) {
  int tid = threadIdx.x;
  int tag = tid & 15, pg = tid >> 4;
  float tr0 = trans[tag * 16 + pg * 4 + 0];
  float tr1 = trans[tag * 16 + pg * 4 + 1];
  float tr2 = trans[tag * 16 + pg * 4 + 2];
  float tr3 = trans[tag * 16 + pg * 4 + 3];
  float s = (tag == 14) ? 0.0f : -10000.0f;   // START=14
  float ft = feats[tag];                       // t=0 prefetch
  for (int t = 0; t < T_SEQ; t++) {
    float ftn = (t + 1 < T_SEQ) ? feats[(t + 1) * 16 + tag] : 0.0f;
    // candidates for prev = pg*4+e  (s[p] lives in lane p, pg0 copy)
    float c0 = __shfl(s, pg * 4 + 0, 64) + tr0;
    float c1 = __shfl(s, pg * 4 + 1, 64) + tr1;
    float c2 = __shfl(s, pg * 4 + 2, 64) + tr2;
    float c3 = __shfl(s, pg * 4 + 3, 64) + tr3;
    float bv = c0; int bi = pg * 4;
    if (c1 > bv) { bv = c1; bi = pg * 4 + 1; }
    if (c2 > bv) { bv = c2; bi = pg * 4 + 2; }
    if (c3 > bv) { bv = c3; bi = pg * 4 + 3; }
    // xor-reduce over the 4 pgroups; ties -> smaller prev index
    float ov = __shfl_xor(bv, 16, 64); int oi = __shfl_xor(bi, 16, 64);
    if (ov > bv || (ov == bv && oi < bi)) { bv = ov; bi = oi; }
    ov = __shfl_xor(bv, 32, 64); oi = __shfl_xor(bi, 32, 64);
    if (ov > bv || (ov == bv && oi < bi)) { bv = ov; bi = oi; }
    s = bv + ft;
    ft = ftn;
    if (pg == 0) bptr[t * 16 + tag] = bi;
  }
  s += trans[15 * 16 + tag];                   // STOP=15
  // argmax over tags (ties -> smaller tag), xor tree within each 16-group
  float bv = s; int bi = tag;
  for (int mask = 1; mask < 16; mask <<= 1) {
    float ov = __shfl_xor(bv, mask, 16); int oi = __shfl_xor(bi, mask, 16);
    if (ov > bv || (ov == bv && oi < bi)) { bv = ov; bi = oi; }
  }
  if (tid == 0) out[0] = bv;
  int bt = bi;                                 // identical in all lanes
  for (int i = tid; i < T_SEQ - 1; i += 64)
    out[1 + i] = (float)bptr[(i + 1) * 16 + bt];
  if (tid == 0) out[T_SEQ] = (float)bt;
}

extern "C" void kernel_launch(void* const* d_in, const int* in_sizes, int n_in,
                              void* d_out, int out_size, void* d_ws, size_t ws_size,
                              hipStream_t stream) {
  const int*   sent  = (const int*)d_in[0];
  const float* embed = (const float*)d_in[1];
  const float* wih0  = (const float*)d_in[2];
  const float* whh0  = (const float*)d_in[3];
  const float* bih0  = (const float*)d_in[4];
  const float* bhh0  = (const float*)d_in[5];
  const float* wih1  = (const float*)d_in[6];
  const float* whh1  = (const float*)d_in[7];
  const float* bih1  = (const float*)d_in[8];
  const float* bhh1  = (const float*)d_in[9];
  const float* w_out = (const float*)d_in[10];
  const float* b_out = (const float*)d_in[11];
  const float* trans = (const float*)d_in[12];
  const float* h0    = (const float*)d_in[13];
  const float* c0    = (const float*)d_in[14];
  float* out = (float*)d_out;

  char* ws = (char*)d_ws;
  float* x0    = (float*)(ws + 0);
  float* x1    = (float*)(ws + 8388608);
  float* x2    = (float*)(ws + 25165824);
  float* gin   = (float*)(ws + 41943040);
  float* feats = (float*)(ws + 109051904);
  int*   bptr  = (int*)(ws + 109314048);
  unsigned long long* hcomm = (unsigned long long*)(ws + 109576192);

  embed_k<<<T_SEQ, 256, 0, stream>>>(sent, embed, x0);

  // layer 0
  gin_gemm_k<<<dim3(16, 32, 2), 256, 0, stream>>>(x0, 512, wih0, bih0, bhh0, 500, gin);
  hinit_k<<<2, 1024, 0, stream>>>(h0, 0, hcomm);
  lstm_k<<<64, 1024, 0, stream>>>(whh0, gin, c0, x1, hcomm, 0);

  // layer 1
  gin_gemm_k<<<dim3(16, 32, 2), 256, 0, stream>>>(x1, 1024, wih1, bih1, bhh1, 1000, gin);
  hinit_k<<<2, 1024, 0, stream>>>(h0, 1, hcomm);
  lstm_k<<<64, 1024, 0, stream>>>(whh1, gin, c0, x2, hcomm, 1);

  // output projection + viterbi
  feats_k<<<T_SEQ / 16, 256, 0, stream>>>(x2, w_out, b_out, feats);
  viterbi_k<<<1, 64, 0, stream>>>(feats, trans, bptr, out);
}

// Round 12
// 15156.601 us; speedup vs baseline: 1.0215x; 1.0215x over previous
//
#include <hip/hip_runtime.h>

// LSTM-CRF on MI355X.
// Pipeline: embed -> gemm(gin L0) -> lstm L0 -> gemm(gin L1) -> lstm L1 -> feats -> viterbi.
// Recurrence: 32 WGs per direction (16 units each), parallel dirs (round-7/10 structure).
// h exchanged per step via tagged u64 {tag:u32, h:f32} device-scope relaxed mailbox.
// Round-11 lesson: shift-register pipelined poll (va=vb;vb=vc;) regressed -- the movs
// force waitcnt on the NEWEST load, so each iteration pays full load latency + 3x traffic.
// Round-12: rotate IN PLACE -- check(va); va=load; check(vb); vb=load; check(vc); vc=load.
// No movs, each check waits only on its own (oldest-outstanding) slot -> sampling period
// ~latency/3 ~ 240cy, cutting the publish->detect alignment term ~350 -> ~120cy.

#define T_SEQ 4096
#define HPAD  512
#define NTAG  16

// ---------------- workspace layout (bytes) ----------------
// x0   : [4096][512]  f32   8388608  @ 0
// x1   : [4096][1024] f32  16777216  @ 8388608
// x2   : [4096][1024] f32  16777216  @ 25165824
// gin  : [2][4096][2048] f32 67108864 @ 41943040
// feats: [4096][16] f32     262144  @ 109051904
// bptr : [4096][16] i32     262144  @ 109314048
// hcomm: [2][2][512] u64     16384  @ 109576192

__global__ void embed_k(const int* __restrict__ sent, const float* __restrict__ ew,
                        float* __restrict__ x0) {
  int t = blockIdx.x;
  int row = sent[t];
  for (int k = threadIdx.x; k < HPAD; k += blockDim.x)
    x0[(size_t)t * HPAD + k] = (k < 500) ? ew[(size_t)row * 500 + k] : 0.0f;
}

// G[dir][t][n] = sum_k A[t][k] * Wmap[dir][n][k] + bias[n]  (f32, 128x128 tile, 8x8/thread)
__global__ __launch_bounds__(256) void gin_gemm_k(
    const float* __restrict__ A, int KA,
    const float* __restrict__ wih, const float* __restrict__ bih,
    const float* __restrict__ bhh, int Kreal, float* __restrict__ G) {
  const int dir = blockIdx.z;
  const int bm = blockIdx.y, bn = blockIdx.x;
  const float* W = wih + (size_t)dir * 2000 * Kreal;

  __shared__ float As[16][128];
  __shared__ float Bs[16][128];

  const int tid = threadIdx.x;
  const int tx = tid & 15, ty = tid >> 4;
  float acc[8][8] = {};

  for (int k0 = 0; k0 < KA; k0 += 16) {
#pragma unroll
    for (int q = 0; q < 2; q++) {
      int f4 = tid + q * 256;              // 0..511
      int m = f4 >> 2, kc = (f4 & 3) * 4;
      float4 av = *reinterpret_cast<const float4*>(A + (size_t)(bm * 128 + m) * KA + k0 + kc);
      As[kc + 0][m] = av.x; As[kc + 1][m] = av.y;
      As[kc + 2][m] = av.z; As[kc + 3][m] = av.w;
    }
#pragma unroll
    for (int q = 0; q < 2; q++) {
      int f4 = tid + q * 256;
      int n = f4 >> 2, kc = (f4 & 3) * 4;
      int nn = bn * 128 + n;
      int gate = nn >> 9, j = nn & 511;
      int k = k0 + kc;
      int jk = k & 511, half = k >> 9;
      // jk is a multiple of 4, so jk<500 => jk<=496 => all 4 elements valid.
      // W row bases are multiples of 16B (500*4, 1000*4, 2000B all 16-aligned).
      float4 bv = {0.0f, 0.0f, 0.0f, 0.0f};
      if (j < 500 && jk < 500)
        bv = *reinterpret_cast<const float4*>(
            &W[(size_t)(gate * 500 + j) * Kreal + half * 500 + jk]);
      Bs[kc + 0][n] = bv.x; Bs[kc + 1][n] = bv.y;
      Bs[kc + 2][n] = bv.z; Bs[kc + 3][n] = bv.w;
    }
    __syncthreads();
#pragma unroll
    for (int kk = 0; kk < 16; kk++) {
      float a[8], b[8];
      *reinterpret_cast<float4*>(&a[0]) = *reinterpret_cast<const float4*>(&As[kk][ty * 8]);
      *reinterpret_cast<float4*>(&a[4]) = *reinterpret_cast<const float4*>(&As[kk][ty * 8 + 4]);
      *reinterpret_cast<float4*>(&b[0]) = *reinterpret_cast<const float4*>(&Bs[kk][tx * 8]);
      *reinterpret_cast<float4*>(&b[4]) = *reinterpret_cast<const float4*>(&Bs[kk][tx * 8 + 4]);
#pragma unroll
      for (int i = 0; i < 8; i++)
#pragma unroll
        for (int j = 0; j < 8; j++) acc[i][j] = fmaf(a[i], b[j], acc[i][j]);
    }
    __syncthreads();
  }
#pragma unroll
  for (int i = 0; i < 8; i++) {
#pragma unroll
    for (int j = 0; j < 8; j++) {
      int m = bm * 128 + ty * 8 + i;
      int nn = bn * 128 + tx * 8 + j;
      int gate = nn >> 9, ju = nn & 511;
      float o = 0.0f;
      if (ju < 500) {
        int r = gate * 500 + ju;
        o = acc[i][j] + bih[dir * 2000 + r] + bhh[dir * 2000 + r];
      }
      G[((size_t)dir * T_SEQ + m) * 2048 + nn] = o;
    }
  }
}

__device__ __forceinline__ unsigned long long pack_hv(unsigned tag, float h) {
  return (unsigned long long)tag | ((unsigned long long)__float_as_uint(h) << 32);
}

// fast sigmoid/tanh: v_exp_f32 + v_rcp_f32, branch-free, saturates correctly.
__device__ __forceinline__ float fsig(float x) {
  float e = __expf(-x);
  return __builtin_amdgcn_rcpf(1.0f + e);
}
__device__ __forceinline__ float ftanhf(float x) {
  return fmaf(2.0f, fsig(x + x), -1.0f);
}

__global__ void hinit_k(const float* __restrict__ h0, int layer,
                        unsigned long long* __restrict__ hcomm) {
  int i = blockIdx.x * blockDim.x + threadIdx.x;   // 0..2047
  int dir = i >> 10, par = (i >> 9) & 1, j = i & 511;
  unsigned long long v;
  if (par == 0) {
    float h = (j < 500) ? h0[(layer * 2 + dir) * 500 + j] : 0.0f;
    v = pack_hv(0u, h);
  } else {
    v = 0xFFFFFFFFull;   // sentinel tag, value 0
  }
  hcomm[(size_t)(dir * 2 + par) * HPAD + j] = v;
}

#define HLOAD(dst) \
  dst = __hip_atomic_load(hp, __ATOMIC_RELAXED, __HIP_MEMORY_SCOPE_AGENT)

// Persistent recurrence kernel: 64 WGs x 1024 threads; WG = (dir = blockIdx>>5,
// wgd = blockIdx&31) owns units [wgd*16, wgd*16+16)  (64 rows = 4 gates x 16 units).
// Wave w owns k-slice [w*32, w*32+32); lane owns ONE row (gate=lane>>4, unit=lane&15).
// One barrier per step; wave0 sums 16 partials per row (pairwise tree), fast gates,
// publishes. Poll is 3-slot rotate-in-place (no register moves).
__global__ __launch_bounds__(1024)
__attribute__((amdgpu_waves_per_eu(4, 4)))
void lstm_k(
    const float* __restrict__ whh_base,   // [2][2000][500]
    const float* __restrict__ gin,        // [2][4096][2048]
    const float* __restrict__ c0,         // [4][500]
    float* __restrict__ xout,             // [4096][1024]
    unsigned long long* __restrict__ hcomm, // [2][2][512]
    int layer) {
  __shared__ float part[16][68];          // pad 68: conflict-free on both patterns
  __shared__ float hbuf[16][32];

  const int tid = threadIdx.x;
  const int dir = blockIdx.x >> 5;
  const int wgd = blockIdx.x & 31;        // unit block [wgd*16, wgd*16+16)
  const int w = tid >> 6;
  const int lane = tid & 63;

  const int gate = lane >> 4;             // my row's gate (0=i,1=f,2=g,3=o)
  const int ul   = lane & 15;             // my row's local unit
  const int j    = wgd * 16 + ul;         // global unit (0..511)
  const int row  = gate * 500 + j;

  // ---- load recurrent weights into registers (1 row x 32 k per lane) ----
  float wreg[32];
  const float* Wd = whh_base + (size_t)dir * 2000 * 500;
#pragma unroll
  for (int i = 0; i < 32; i++) {
    int k = w * 32 + i;
    wreg[i] = (j < 500 && k < 500) ? Wd[(size_t)row * 500 + k] : 0.0f;
  }
#pragma unroll
  for (int i = 0; i < 32; i++) asm volatile("" : "+v"(wreg[i]));

  // wave0 lanes<16: persistent cell state (one unit per lane)
  float c = 0.0f;
  if (w == 0 && lane < 16 && j < 500) c = c0[(layer * 2 + dir) * 500 + j];

  unsigned long long* hcd = hcomm + (size_t)dir * 2 * HPAD;
  bool dead = false;

  for (int t = 0; t < T_SEQ; t++) {
    const int t_in = (dir == 0) ? t : (T_SEQ - 1 - t);

    // prefetch input-projection gate value for my row (latency hidden under poll)
    float gi = 0.0f;
    if (w == 0) {
      const float* gb = gin + ((size_t)dir * T_SEQ + t_in) * 2048;
      gi = gb[gate * 512 + j];
    }

    // ---- 3-slot rotate-in-place poll of my h slot (tag==t), device-scope ----
    unsigned long long v = 0;
    if (!dead) {
      const unsigned long long* hp =
          hcd + (size_t)(t & 1) * HPAD + w * 32 + (lane & 31);
      unsigned long long va, vb, vc;
      HLOAD(va); HLOAD(vb); HLOAD(vc);
      int guard = 0;
      for (;;) {
        if (__all((int)((unsigned)va == (unsigned)t))) { v = va; break; }
        HLOAD(va);
        if (__all((int)((unsigned)vb == (unsigned)t))) { v = vb; break; }
        HLOAD(vb);
        if (__all((int)((unsigned)vc == (unsigned)t))) { v = vc; break; }
        HLOAD(vc);
        if ((guard += 3) > (1 << 22)) { dead = true; break; }   // bail, never hang
      }
    }
    float hval = __uint_as_float((unsigned)(v >> 32));

    // ---- broadcast h within the wave via LDS, matvec partial for my row ----
    if (lane < 32) hbuf[w][lane] = hval;   // same-wave RAW, ordered by lgkmcnt
    float a = 0.0f;
#pragma unroll
    for (int b = 0; b < 8; b++) {
      float4 hv = *reinterpret_cast<const float4*>(&hbuf[w][b * 4]);
      a = fmaf(wreg[b * 4 + 0], hv.x, a);
      a = fmaf(wreg[b * 4 + 1], hv.y, a);
      a = fmaf(wreg[b * 4 + 2], hv.z, a);
      a = fmaf(wreg[b * 4 + 3], hv.w, a);
    }
    part[w][lane] = a;
    __syncthreads();   // the ONLY barrier per step

    // ---- wave0: pairwise tree-sum of 16 partials, fast gates, publish ----
    // Race-free vs next step: waves can only overwrite part(t+1) after polling
    // h(t+1), which requires the publish below -- which follows these reads.
    if (w == 0) {
      __builtin_amdgcn_s_setprio(1);       // win issue arbitration vs spinning waves
      float p0 = part[0][lane] + part[1][lane];
      float p1 = part[2][lane] + part[3][lane];
      float p2 = part[4][lane] + part[5][lane];
      float p3 = part[6][lane] + part[7][lane];
      float p4 = part[8][lane] + part[9][lane];
      float p5 = part[10][lane] + part[11][lane];
      float p6 = part[12][lane] + part[13][lane];
      float p7 = part[14][lane] + part[15][lane];
      float q0 = p0 + p1, q1 = p2 + p3, q2 = p4 + p5, q3 = p6 + p7;
      float s = gi + ((q0 + q1) + (q2 + q3));
      float nl = (gate == 2) ? ftanhf(s) : fsig(s);
      float xf = __shfl(nl, lane + 16, 64);
      float xg = __shfl(nl, lane + 32, 64);
      float xo = __shfl(nl, lane + 48, 64);
      if (lane < 16) {
        c = xf * c + nl * xg;              // nl here is xi (gate 0)
        float h = xo * ftanhf(c);
        // publish FIRST (starts the LLC trip), then the xout store
        __hip_atomic_store(hcd + (size_t)((t + 1) & 1) * HPAD + j,
                           pack_hv((unsigned)(t + 1), h),
                           __ATOMIC_RELAXED, __HIP_MEMORY_SCOPE_AGENT);
        if (j < 500)
          xout[(size_t)t_in * 1024 + (size_t)dir * HPAD + j] = h;
      }
      __builtin_amdgcn_s_setprio(0);
    }
  }
}

// feats[t][tag] = sum_k x2[t][k]*w_out[tag][k_real] + b_out[tag]
__global__ __launch_bounds__(256) void feats_k(
    const float* __restrict__ x2, const float* __restrict__ w_out,
    const float* __restrict__ b_out, float* __restrict__ feats) {
  int tid = threadIdx.x;
  int tag = tid & 15, tl = tid >> 4;
  int t = blockIdx.x * 16 + tl;
  float a0 = 0.0f, a1 = 0.0f, a2 = 0.0f, a3 = 0.0f;
  for (int k = 0; k < 1024; k += 4) {
    int jk = k & 511;   // k%4==0 so all 4 share the same half; jk+3<500 iff jk<500-3
    const float* xr = x2 + (size_t)t * 1024 + k;
    const float* wr = w_out + tag * 1000 + (k >> 9) * 500 + jk;
    if (jk + 3 < 500) {
      a0 = fmaf(xr[0], wr[0], a0);
      a1 = fmaf(xr[1], wr[1], a1);
      a2 = fmaf(xr[2], wr[2], a2);
      a3 = fmaf(xr[3], wr[3], a3);
    } else if (jk < 500) {
#pragma unroll
      for (int e = 0; e < 4; e++)
        if (jk + e < 500) a0 = fmaf(xr[e], wr[e], a0);
    }
  }
  feats[t * 16 + tag] = ((a0 + a1) + (a2 + a3)) + b_out[tag];
}

// Viterbi: one wave. lane = pg*16 + tag (pg = prev-group of 4). Tree argmax with
// np.argmax tie-break (smallest prev index). feats prefetched one step ahead.
__global__ __launch_bounds__(64) void viterbi_k(
    const float* __restrict__ feats, const float* __restrict__ trans,
    int* __restrict__ bptr, float* __restrict__ out) {
  int tid = threadIdx.x;
  int tag = tid & 15, pg = tid >> 4;
  float tr0 = trans[tag * 16 + pg * 4 + 0];
  float tr1 = trans[tag * 16 + pg * 4 + 1];
  float tr2 = trans[tag * 16 + pg * 4 + 2];
  float tr3 = trans[tag * 16 + pg * 4 + 3];
  float s = (tag == 14) ? 0.0f : -10000.0f;   // START=14
  float ft = feats[tag];                       // t=0 prefetch
  for (int t = 0; t < T_SEQ; t++) {
    float ftn = (t + 1 < T_SEQ) ? feats[(t + 1) * 16 + tag] : 0.0f;
    // candidates for prev = pg*4+e  (s[p] lives in lane p, pg0 copy)
    float c0 = __shfl(s, pg * 4 + 0, 64) + tr0;
    float c1 = __shfl(s, pg * 4 + 1, 64) + tr1;
    float c2 = __shfl(s, pg * 4 + 2, 64) + tr2;
    float c3 = __shfl(s, pg * 4 + 3, 64) + tr3;
    float bv = c0; int bi = pg * 4;
    if (c1 > bv) { bv = c1; bi = pg * 4 + 1; }
    if (c2 > bv) { bv = c2; bi = pg * 4 + 2; }
    if (c3 > bv) { bv = c3; bi = pg * 4 + 3; }
    // xor-reduce over the 4 pgroups; ties -> smaller prev index
    float ov = __shfl_xor(bv, 16, 64); int oi = __shfl_xor(bi, 16, 64);
    if (ov > bv || (ov == bv && oi < bi)) { bv = ov; bi = oi; }
    ov = __shfl_xor(bv, 32, 64); oi = __shfl_xor(bi, 32, 64);
    if (ov > bv || (ov == bv && oi < bi)) { bv = ov; bi = oi; }
    s = bv + ft;
    ft = ftn;
    if (pg == 0) bptr[t * 16 + tag] = bi;
  }
  s += trans[15 * 16 + tag];                   // STOP=15
  // argmax over tags (ties -> smaller tag), xor tree within each 16-group
  float bv = s; int bi = tag;
  for (int mask = 1; mask < 16; mask <<= 1) {
    float ov = __shfl_xor(bv, mask, 16); int oi = __shfl_xor(bi, mask, 16);
    if (ov > bv || (ov == bv && oi < bi)) { bv = ov; bi = oi; }
  }
  if (tid == 0) out[0] = bv;
  int bt = bi;                                 // identical in all lanes
  for (int i = tid; i < T_SEQ - 1; i += 64)
    out[1 + i] = (float)bptr[(i + 1) * 16 + bt];
  if (tid == 0) out[T_SEQ] = (float)bt;
}

extern "C" void kernel_launch(void* const* d_in, const int* in_sizes, int n_in,
                              void* d_out, int out_size, void* d_ws, size_t ws_size,
                              hipStream_t stream) {
  const int*   sent  = (const int*)d_in[0];
  const float* embed = (const float*)d_in[1];
  const float* wih0  = (const float*)d_in[2];
  const float* whh0  = (const float*)d_in[3];
  const float* bih0  = (const float*)d_in[4];
  const float* bhh0  = (const float*)d_in[5];
  const float* wih1  = (const float*)d_in[6];
  const float* whh1  = (const float*)d_in[7];
  const float* bih1  = (const float*)d_in[8];
  const float* bhh1  = (const float*)d_in[9];
  const float* w_out = (const float*)d_in[10];
  const float* b_out = (const float*)d_in[11];
  const float* trans = (const float*)d_in[12];
  const float* h0    = (const float*)d_in[13];
  const float* c0    = (const float*)d_in[14];
  float* out = (float*)d_out;

  char* ws = (char*)d_ws;
  float* x0    = (float*)(ws + 0);
  float* x1    = (float*)(ws + 8388608);
  float* x2    = (float*)(ws + 25165824);
  float* gin   = (float*)(ws + 41943040);
  float* feats = (float*)(ws + 109051904);
  int*   bptr  = (int*)(ws + 109314048);
  unsigned long long* hcomm = (unsigned long long*)(ws + 109576192);

  embed_k<<<T_SEQ, 256, 0, stream>>>(sent, embed, x0);

  // layer 0
  gin_gemm_k<<<dim3(16, 32, 2), 256, 0, stream>>>(x0, 512, wih0, bih0, bhh0, 500, gin);
  hinit_k<<<2, 1024, 0, stream>>>(h0, 0, hcomm);
  lstm_k<<<64, 1024, 0, stream>>>(whh0, gin, c0, x1, hcomm, 0);

  // layer 1
  gin_gemm_k<<<dim3(16, 32, 2), 256, 0, stream>>>(x1, 1024, wih1, bih1, bhh1, 1000, gin);
  hinit_k<<<2, 1024, 0, stream>>>(h0, 1, hcomm);
  lstm_k<<<64, 1024, 0, stream>>>(whh1, gin, c0, x2, hcomm, 1);

  // output projection + viterbi
  feats_k<<<T_SEQ / 16, 256, 0, stream>>>(x2, w_out, b_out, feats);
  viterbi_k<<<1, 64, 0, stream>>>(feats, trans, bptr, out);
}

// Round 13
// 13111.543 us; speedup vs baseline: 1.1809x; 1.1560x over previous
//
#include <hip/hip_runtime.h>

// LSTM-CRF on MI355X.
// Pipeline: embed -> gemm(gin L0) -> lstm L0 -> gemm(gin L1) -> lstm L1 -> feats -> viterbi.
// Recurrence: 32 WGs per direction (16 units each), parallel dirs (round-7/10 structure).
// h exchanged per step via tagged u64 {tag:u32, h:f32} device-scope relaxed mailbox.
// Poll: SIMPLE spin (round-10). Rounds 11/12 proved multi-slot pipelined polling regresses
// at HIP level (vmcnt is issue-ordered; atomic re-loads serialize/drain) -- simple is best.
// This round = union of all verified wins: round-10 lstm + round-11/12 non-lstm kernels
// (one-wave viterbi, float4 B-staging, ILP feats, no zero_k).

#define T_SEQ 4096
#define HPAD  512
#define NTAG  16

// ---------------- workspace layout (bytes) ----------------
// x0   : [4096][512]  f32   8388608  @ 0
// x1   : [4096][1024] f32  16777216  @ 8388608
// x2   : [4096][1024] f32  16777216  @ 25165824
// gin  : [2][4096][2048] f32 67108864 @ 41943040
// feats: [4096][16] f32     262144  @ 109051904
// bptr : [4096][16] i32     262144  @ 109314048
// hcomm: [2][2][512] u64     16384  @ 109576192

__global__ void embed_k(const int* __restrict__ sent, const float* __restrict__ ew,
                        float* __restrict__ x0) {
  int t = blockIdx.x;
  int row = sent[t];
  for (int k = threadIdx.x; k < HPAD; k += blockDim.x)
    x0[(size_t)t * HPAD + k] = (k < 500) ? ew[(size_t)row * 500 + k] : 0.0f;
}

// G[dir][t][n] = sum_k A[t][k] * Wmap[dir][n][k] + bias[n]  (f32, 128x128 tile, 8x8/thread)
__global__ __launch_bounds__(256) void gin_gemm_k(
    const float* __restrict__ A, int KA,
    const float* __restrict__ wih, const float* __restrict__ bih,
    const float* __restrict__ bhh, int Kreal, float* __restrict__ G) {
  const int dir = blockIdx.z;
  const int bm = blockIdx.y, bn = blockIdx.x;
  const float* W = wih + (size_t)dir * 2000 * Kreal;

  __shared__ float As[16][128];
  __shared__ float Bs[16][128];

  const int tid = threadIdx.x;
  const int tx = tid & 15, ty = tid >> 4;
  float acc[8][8] = {};

  for (int k0 = 0; k0 < KA; k0 += 16) {
#pragma unroll
    for (int q = 0; q < 2; q++) {
      int f4 = tid + q * 256;              // 0..511
      int m = f4 >> 2, kc = (f4 & 3) * 4;
      float4 av = *reinterpret_cast<const float4*>(A + (size_t)(bm * 128 + m) * KA + k0 + kc);
      As[kc + 0][m] = av.x; As[kc + 1][m] = av.y;
      As[kc + 2][m] = av.z; As[kc + 3][m] = av.w;
    }
#pragma unroll
    for (int q = 0; q < 2; q++) {
      int f4 = tid + q * 256;
      int n = f4 >> 2, kc = (f4 & 3) * 4;
      int nn = bn * 128 + n;
      int gate = nn >> 9, j = nn & 511;
      int k = k0 + kc;
      int jk = k & 511, half = k >> 9;
      // jk is a multiple of 4, so jk<500 => jk<=496 => all 4 elements valid.
      // W row bases are multiples of 16B (500*4, 1000*4, 2000B all 16-aligned).
      float4 bv = {0.0f, 0.0f, 0.0f, 0.0f};
      if (j < 500 && jk < 500)
        bv = *reinterpret_cast<const float4*>(
            &W[(size_t)(gate * 500 + j) * Kreal + half * 500 + jk]);
      Bs[kc + 0][n] = bv.x; Bs[kc + 1][n] = bv.y;
      Bs[kc + 2][n] = bv.z; Bs[kc + 3][n] = bv.w;
    }
    __syncthreads();
#pragma unroll
    for (int kk = 0; kk < 16; kk++) {
      float a[8], b[8];
      *reinterpret_cast<float4*>(&a[0]) = *reinterpret_cast<const float4*>(&As[kk][ty * 8]);
      *reinterpret_cast<float4*>(&a[4]) = *reinterpret_cast<const float4*>(&As[kk][ty * 8 + 4]);
      *reinterpret_cast<float4*>(&b[0]) = *reinterpret_cast<const float4*>(&Bs[kk][tx * 8]);
      *reinterpret_cast<float4*>(&b[4]) = *reinterpret_cast<const float4*>(&Bs[kk][tx * 8 + 4]);
#pragma unroll
      for (int i = 0; i < 8; i++)
#pragma unroll
        for (int j = 0; j < 8; j++) acc[i][j] = fmaf(a[i], b[j], acc[i][j]);
    }
    __syncthreads();
  }
#pragma unroll
  for (int i = 0; i < 8; i++) {
#pragma unroll
    for (int j = 0; j < 8; j++) {
      int m = bm * 128 + ty * 8 + i;
      int nn = bn * 128 + tx * 8 + j;
      int gate = nn >> 9, ju = nn & 511;
      float o = 0.0f;
      if (ju < 500) {
        int r = gate * 500 + ju;
        o = acc[i][j] + bih[dir * 2000 + r] + bhh[dir * 2000 + r];
      }
      G[((size_t)dir * T_SEQ + m) * 2048 + nn] = o;
    }
  }
}

__device__ __forceinline__ unsigned long long pack_hv(unsigned tag, float h) {
  return (unsigned long long)tag | ((unsigned long long)__float_as_uint(h) << 32);
}

// fast sigmoid/tanh: v_exp_f32 + v_rcp_f32, branch-free, saturates correctly.
__device__ __forceinline__ float fsig(float x) {
  float e = __expf(-x);
  return __builtin_amdgcn_rcpf(1.0f + e);
}
__device__ __forceinline__ float ftanhf(float x) {
  return fmaf(2.0f, fsig(x + x), -1.0f);
}

__global__ void hinit_k(const float* __restrict__ h0, int layer,
                        unsigned long long* __restrict__ hcomm) {
  int i = blockIdx.x * blockDim.x + threadIdx.x;   // 0..2047
  int dir = i >> 10, par = (i >> 9) & 1, j = i & 511;
  unsigned long long v;
  if (par == 0) {
    float h = (j < 500) ? h0[(layer * 2 + dir) * 500 + j] : 0.0f;
    v = pack_hv(0u, h);
  } else {
    v = 0xFFFFFFFFull;   // sentinel tag, value 0
  }
  hcomm[(size_t)(dir * 2 + par) * HPAD + j] = v;
}

// Persistent recurrence kernel: 64 WGs x 1024 threads; WG = (dir = blockIdx>>5,
// wgd = blockIdx&31) owns units [wgd*16, wgd*16+16)  (64 rows = 4 gates x 16 units).
// Wave w owns k-slice [w*32, w*32+32); lane owns ONE row (gate=lane>>4, unit=lane&15).
// One barrier per step; wave0 sums 16 partials per row (pairwise tree), fast gates,
// publishes. Poll: simple spin (proven optimal; see header).
__global__ __launch_bounds__(1024)
__attribute__((amdgpu_waves_per_eu(4, 4)))
void lstm_k(
    const float* __restrict__ whh_base,   // [2][2000][500]
    const float* __restrict__ gin,        // [2][4096][2048]
    const float* __restrict__ c0,         // [4][500]
    float* __restrict__ xout,             // [4096][1024]
    unsigned long long* __restrict__ hcomm, // [2][2][512]
    int layer) {
  __shared__ float part[16][68];          // pad 68: conflict-free on both patterns
  __shared__ float hbuf[16][32];

  const int tid = threadIdx.x;
  const int dir = blockIdx.x >> 5;
  const int wgd = blockIdx.x & 31;        // unit block [wgd*16, wgd*16+16)
  const int w = tid >> 6;
  const int lane = tid & 63;

  const int gate = lane >> 4;             // my row's gate (0=i,1=f,2=g,3=o)
  const int ul   = lane & 15;             // my row's local unit
  const int j    = wgd * 16 + ul;         // global unit (0..511)
  const int row  = gate * 500 + j;

  // ---- load recurrent weights into registers (1 row x 32 k per lane) ----
  float wreg[32];
  const float* Wd = whh_base + (size_t)dir * 2000 * 500;
#pragma unroll
  for (int i = 0; i < 32; i++) {
    int k = w * 32 + i;
    wreg[i] = (j < 500 && k < 500) ? Wd[(size_t)row * 500 + k] : 0.0f;
  }
#pragma unroll
  for (int i = 0; i < 32; i++) asm volatile("" : "+v"(wreg[i]));

  // wave0 lanes<16: persistent cell state (one unit per lane)
  float c = 0.0f;
  if (w == 0 && lane < 16 && j < 500) c = c0[(layer * 2 + dir) * 500 + j];

  unsigned long long* hcd = hcomm + (size_t)dir * 2 * HPAD;
  bool dead = false;

  for (int t = 0; t < T_SEQ; t++) {
    const int t_in = (dir == 0) ? t : (T_SEQ - 1 - t);

    // prefetch input-projection gate value for my row (latency hidden under poll)
    float gi = 0.0f;
    if (w == 0) {
      const float* gb = gin + ((size_t)dir * T_SEQ + t_in) * 2048;
      gi = gb[gate * 512 + j];
    }

    // ---- poll my wave's h k-slice (tag==t), device-scope, simple spin ----
    unsigned long long v = 0;
    if (!dead) {
      const unsigned long long* hp =
          hcd + (size_t)(t & 1) * HPAD + w * 32 + (lane & 31);
      int guard = 0;
      for (;;) {
        v = __hip_atomic_load(hp, __ATOMIC_RELAXED, __HIP_MEMORY_SCOPE_AGENT);
        if (__all((int)((unsigned)v == (unsigned)t))) break;
        if (++guard > (1 << 22)) { dead = true; break; }   // bail, never hang
      }
    }
    float hval = __uint_as_float((unsigned)(v >> 32));

    // ---- broadcast h within the wave via LDS, matvec partial for my row ----
    if (lane < 32) hbuf[w][lane] = hval;   // same-wave RAW, ordered by lgkmcnt
    float a = 0.0f;
#pragma unroll
    for (int b = 0; b < 8; b++) {
      float4 hv = *reinterpret_cast<const float4*>(&hbuf[w][b * 4]);
      a = fmaf(wreg[b * 4 + 0], hv.x, a);
      a = fmaf(wreg[b * 4 + 1], hv.y, a);
      a = fmaf(wreg[b * 4 + 2], hv.z, a);
      a = fmaf(wreg[b * 4 + 3], hv.w, a);
    }
    part[w][lane] = a;
    __syncthreads();   // the ONLY barrier per step

    // ---- wave0: pairwise tree-sum of 16 partials, fast gates, publish ----
    // Race-free vs next step: waves can only overwrite part(t+1) after polling
    // h(t+1), which requires the publish below -- which follows these reads.
    if (w == 0) {
      __builtin_amdgcn_s_setprio(1);       // win issue arbitration vs spinning waves
      float p0 = part[0][lane] + part[1][lane];
      float p1 = part[2][lane] + part[3][lane];
      float p2 = part[4][lane] + part[5][lane];
      float p3 = part[6][lane] + part[7][lane];
      float p4 = part[8][lane] + part[9][lane];
      float p5 = part[10][lane] + part[11][lane];
      float p6 = part[12][lane] + part[13][lane];
      float p7 = part[14][lane] + part[15][lane];
      float q0 = p0 + p1, q1 = p2 + p3, q2 = p4 + p5, q3 = p6 + p7;
      float s = gi + ((q0 + q1) + (q2 + q3));
      float nl = (gate == 2) ? ftanhf(s) : fsig(s);
      float xf = __shfl(nl, lane + 16, 64);
      float xg = __shfl(nl, lane + 32, 64);
      float xo = __shfl(nl, lane + 48, 64);
      if (lane < 16) {
        c = xf * c + nl * xg;              // nl here is xi (gate 0)
        float h = xo * ftanhf(c);
        // publish FIRST (starts the LLC trip), then the xout store
        __hip_atomic_store(hcd + (size_t)((t + 1) & 1) * HPAD + j,
                           pack_hv((unsigned)(t + 1), h),
                           __ATOMIC_RELAXED, __HIP_MEMORY_SCOPE_AGENT);
        if (j < 500)
          xout[(size_t)t_in * 1024 + (size_t)dir * HPAD + j] = h;
      }
      __builtin_amdgcn_s_setprio(0);
    }
  }
}

// feats[t][tag] = sum_k x2[t][k]*w_out[tag][k_real] + b_out[tag]
__global__ __launch_bounds__(256) void feats_k(
    const float* __restrict__ x2, const float* __restrict__ w_out,
    const float* __restrict__ b_out, float* __restrict__ feats) {
  int tid = threadIdx.x;
  int tag = tid & 15, tl = tid >> 4;
  int t = blockIdx.x * 16 + tl;
  float a0 = 0.0f, a1 = 0.0f, a2 = 0.0f, a3 = 0.0f;
  for (int k = 0; k < 1024; k += 4) {
    int jk = k & 511;   // k%4==0 so all 4 share the same half; jk+3<500 iff jk<500-3
    const float* xr = x2 + (size_t)t * 1024 + k;
    const float* wr = w_out + tag * 1000 + (k >> 9) * 500 + jk;
    if (jk + 3 < 500) {
      a0 = fmaf(xr[0], wr[0], a0);
      a1 = fmaf(xr[1], wr[1], a1);
      a2 = fmaf(xr[2], wr[2], a2);
      a3 = fmaf(xr[3], wr[3], a3);
    } else if (jk < 500) {
#pragma unroll
      for (int e = 0; e < 4; e++)
        if (jk + e < 500) a0 = fmaf(xr[e], wr[e], a0);
    }
  }
  feats[t * 16 + tag] = ((a0 + a1) + (a2 + a3)) + b_out[tag];
}

// Viterbi: one wave. lane = pg*16 + tag (pg = prev-group of 4). Tree argmax with
// np.argmax tie-break (smallest prev index). feats prefetched one step ahead.
__global__ __launch_bounds__(64) void viterbi_k(
    const float* __restrict__ feats, const float* __restrict__ trans,
    int* __restrict__ bptr, float* __restrict__ out) {
  int tid = threadIdx.x;
  int tag = tid & 15, pg = tid >> 4;
  float tr0 = trans[tag * 16 + pg * 4 + 0];
  float tr1 = trans[tag * 16 + pg * 4 + 1];
  float tr2 = trans[tag * 16 + pg * 4 + 2];
  float tr3 = trans[tag * 16 + pg * 4 + 3];
  float s = (tag == 14) ? 0.0f : -10000.0f;   // START=14
  float ft = feats[tag];                       // t=0 prefetch
  for (int t = 0; t < T_SEQ; t++) {
    float ftn = (t + 1 < T_SEQ) ? feats[(t + 1) * 16 + tag] : 0.0f;
    // candidates for prev = pg*4+e  (s[p] lives in lane p, pg0 copy)
    float c0 = __shfl(s, pg * 4 + 0, 64) + tr0;
    float c1 = __shfl(s, pg * 4 + 1, 64) + tr1;
    float c2 = __shfl(s, pg * 4 + 2, 64) + tr2;
    float c3 = __shfl(s, pg * 4 + 3, 64) + tr3;
    float bv = c0; int bi = pg * 4;
    if (c1 > bv) { bv = c1; bi = pg * 4 + 1; }
    if (c2 > bv) { bv = c2; bi = pg * 4 + 2; }
    if (c3 > bv) { bv = c3; bi = pg * 4 + 3; }
    // xor-reduce over the 4 pgroups; ties -> smaller prev index
    float ov = __shfl_xor(bv, 16, 64); int oi = __shfl_xor(bi, 16, 64);
    if (ov > bv || (ov == bv && oi < bi)) { bv = ov; bi = oi; }
    ov = __shfl_xor(bv, 32, 64); oi = __shfl_xor(bi, 32, 64);
    if (ov > bv || (ov == bv && oi < bi)) { bv = ov; bi = oi; }
    s = bv + ft;
    ft = ftn;
    if (pg == 0) bptr[t * 16 + tag] = bi;
  }
  s += trans[15 * 16 + tag];                   // STOP=15
  // argmax over tags (ties -> smaller tag), xor tree within each 16-group
  float bv = s; int bi = tag;
  for (int mask = 1; mask < 16; mask <<= 1) {
    float ov = __shfl_xor(bv, mask, 16); int oi = __shfl_xor(bi, mask, 16);
    if (ov > bv || (ov == bv && oi < bi)) { bv = ov; bi = oi; }
  }
  if (tid == 0) out[0] = bv;
  int bt = bi;                                 // identical in all lanes
  for (int i = tid; i < T_SEQ - 1; i += 64)
    out[1 + i] = (float)bptr[(i + 1) * 16 + bt];
  if (tid == 0) out[T_SEQ] = (float)bt;
}

extern "C" void kernel_launch(void* const* d_in, const int* in_sizes, int n_in,
                              void* d_out, int out_size, void* d_ws, size_t ws_size,
                              hipStream_t stream) {
  const int*   sent  = (const int*)d_in[0];
  const float* embed = (const float*)d_in[1];
  const float* wih0  = (const float*)d_in[2];
  const float* whh0  = (const float*)d_in[3];
  const float* bih0  = (const float*)d_in[4];
  const float* bhh0  = (const float*)d_in[5];
  const float* wih1  = (const float*)d_in[6];
  const float* whh1  = (const float*)d_in[7];
  const float* bih1  = (const float*)d_in[8];
  const float* bhh1  = (const float*)d_in[9];
  const float* w_out = (const float*)d_in[10];
  const float* b_out = (const float*)d_in[11];
  const float* trans = (const float*)d_in[12];
  const float* h0    = (const float*)d_in[13];
  const float* c0    = (const float*)d_in[14];
  float* out = (float*)d_out;

  char* ws = (char*)d_ws;
  float* x0    = (float*)(ws + 0);
  float* x1    = (float*)(ws + 8388608);
  float* x2    = (float*)(ws + 25165824);
  float* gin   = (float*)(ws + 41943040);
  float* feats = (float*)(ws + 109051904);
  int*   bptr  = (int*)(ws + 109314048);
  unsigned long long* hcomm = (unsigned long long*)(ws + 109576192);

  embed_k<<<T_SEQ, 256, 0, stream>>>(sent, embed, x0);

  // layer 0
  gin_gemm_k<<<dim3(16, 32, 2), 256, 0, stream>>>(x0, 512, wih0, bih0, bhh0, 500, gin);
  hinit_k<<<2, 1024, 0, stream>>>(h0, 0, hcomm);
  lstm_k<<<64, 1024, 0, stream>>>(whh0, gin, c0, x1, hcomm, 0);

  // layer 1
  gin_gemm_k<<<dim3(16, 32, 2), 256, 0, stream>>>(x1, 1024, wih1, bih1, bhh1, 1000, gin);
  hinit_k<<<2, 1024, 0, stream>>>(h0, 1, hcomm);
  lstm_k<<<64, 1024, 0, stream>>>(whh1, gin, c0, x2, hcomm, 1);

  // output projection + viterbi
  feats_k<<<T_SEQ / 16, 256, 0, stream>>>(x2, w_out, b_out, feats);
  viterbi_k<<<1, 64, 0, stream>>>(feats, trans, bptr, out);
}